// Round 7
// baseline (99.170 us; speedup 1.0000x reference)
//
#include <hip/hip_runtime.h>

// RelativePositionalEncoding2D: out[b,i,j,e] = W[e, pos] + bias[e]
//   pos = clip(idxs[b,j] - idxs[b,i], -32, 32) + 32
// Shapes: B=1, S=1024, E=128, N=65. Output fp32 (1,S,S,E) = 512 MiB -> pure
// HBM-write-bound (floor ~80us at ~6.7 TB/s measured fill BW).
//
// R6 -> R7: break the ds_read -> store dependency for the clipped majority.
// With these inputs ~94% of output rows use p==0 or p==64 (|j-i| >= 32).
// Hoist table[0] and table[64] into registers once; in the loop, clipped
// lanes store straight from registers (no LDS op, no lgkmcnt wait -> fill-
// kernel-like store issue). Only diagonal-band waves take the guarded
// ds_read path (exec-mask skip when no lane is interior). Data-driven
// branch — correct for arbitrary idxs. Everything else identical to R6.

#define MAXGAP 32
#define NIDX   65     // 2*MAXGAP+1
#define EDIM   128
#define E4     32     // EDIM/4 float4 per output row
#define PADE   132    // padded row stride in floats (528B, 16B-aligned)
#define CHUNKS 2      // half-rows per i

typedef float f32x4 __attribute__((ext_vector_type(4)));

__global__ __launch_bounds__(256) void relpos2d_kernel(
    const int* __restrict__ idxs,
    const float* __restrict__ W,       // (E, N) row-major
    const float* __restrict__ bias,    // (E,)
    f32x4* __restrict__ out,           // (S*S, E4)
    int S, int halfS)
{
    __shared__ float table[NIDX * PADE];  // 65*132*4 = 34,320 B
    __shared__ int   jidx[512];           // halfS entries

    // table[p][e] = W[e*N + p] + bias[e]; read W coalesced, scatter to LDS.
    for (int t = threadIdx.x; t < NIDX * EDIM; t += 256) {
        float w = W[t];              // coalesced: t = e*NIDX + p
        int e = t / NIDX;            // magic-mul (constant divisor)
        int p = t - e * NIDX;
        table[p * PADE + e] = w + bias[e];
    }

    const int i     = blockIdx.x >> 1;       // CHUNKS == 2
    const int chunk = blockIdx.x & (CHUNKS - 1);
    const int jbase = chunk * halfS;

    // stage this block's idxs[j] slice
    for (int t = threadIdx.x; t < halfS; t += 256)
        jidx[t] = idxs[jbase + t];

    __syncthreads();

    const int lane4 = threadIdx.x & 31;   // float4 slot within the 512B row
    const int jsub  = threadIdx.x >> 5;   // 0..7: j within this step
    const int idx_i = idxs[i];

    // Register-resident values for the two clipped positions (the vast
    // majority of the output when idxs is near-monotone).
    const f32x4 v_lo = reinterpret_cast<const f32x4*>(&table[0])[lane4];
    const f32x4 v_hi = reinterpret_cast<const f32x4*>(&table[(NIDX - 1) * PADE])[lane4];

    f32x4* __restrict__ orow = out + (size_t)i * S * E4 + (size_t)jbase * E4;

    #pragma unroll 4
    for (int jj = 0; jj < halfS; jj += 8) {
        int j = jj + jsub;
        int d = jidx[j] - idx_i;                       // LDS broadcast read
        f32x4 v;
        if (d >= MAXGAP)       v = v_hi;               // register, no LDS
        else if (d <= -MAXGAP) v = v_lo;               // register, no LDS
        else                                            // rare band: ds_read
            v = reinterpret_cast<const f32x4*>(&table[(d + MAXGAP) * PADE])[lane4];

        orow[(size_t)j * E4 + lane4] = v;
    }
}

extern "C" void kernel_launch(void* const* d_in, const int* in_sizes, int n_in,
                              void* d_out, int out_size, void* d_ws, size_t ws_size,
                              hipStream_t stream) {
    const int*   idxs = (const int*)  d_in[0];   // (B*S,) int32, B=1
    const float* W    = (const float*)d_in[1];   // (E, N) fp32
    const float* bias = (const float*)d_in[2];   // (E,)  fp32

    f32x4* out = (f32x4*)d_out;

    const int S     = in_sizes[0];   // B=1
    const int halfS = S / 2;
    const int grid  = S * CHUNKS;    // 2048 blocks: one (i, half-row) tile each

    relpos2d_kernel<<<grid, 256, 0, stream>>>(idxs, W, bias, out, S, halfS);
}